// Round 5
// baseline (412.464 us; speedup 1.0000x reference)
//
#include <hip/hip_runtime.h>
#include <stdint.h>

#define B_N   1024
#define D_DIM 512
#define H_DIM 512
#define A_DIM 18
#define T_N   64
#define HTILE 256
#define SMAX  32      // sample slots per fc1 block pass (n_bar=16, max ~30 -> 1 pass)
#define NSB2  8       // head sample-blocks per task

// meta workspace layout (ints): off[0..64] at META_OFF, slist[1024] at META_SLIST
#define META_OFF   0
#define META_SLIST 256
#define META_INTS  2048      // 8 KB reserved before hpre

// Inline task_id dtype detection (int32 vs int64), executed by one full wave.
__device__ __forceinline__ bool taskid_is_int32(const int* raw, int lane) {
    int probe = raw[lane];
    unsigned long long odd = __ballot((lane & 1) && probe != 0);
    return odd != 0ull;
}

// ---------------- K0: bucket task ids once (1 block, 1024 threads) ----------------
__global__ __launch_bounds__(1024) void bucket_kernel(const int* __restrict__ raw,
                                                      int* __restrict__ meta) {
    __shared__ int cnt[T_N];
    __shared__ int base[T_N];
    __shared__ int flag32;
    int tid = threadIdx.x;
    if (tid < 64) {
        bool is32 = taskid_is_int32(raw, tid);
        if (tid == 0) flag32 = is32 ? 1 : 0;
    }
    if (tid < T_N) cnt[tid] = 0;
    __syncthreads();
    int id = flag32 ? raw[tid] : raw[2 * tid];
    atomicAdd(&cnt[id], 1);
    __syncthreads();
    if (tid < 64) {
        int v = cnt[tid];
        int x = v;
#pragma unroll
        for (int o = 1; o < 64; o <<= 1) {          // inclusive scan, wave 0
            int tv = __shfl_up(x, o);
            if (tid >= o) x += tv;
        }
        int excl = x - v;
        meta[META_OFF + tid] = excl;
        base[tid] = excl;
        if (tid == 63) meta[META_OFF + 64] = x;     // = B_N
    }
    __syncthreads();
    int pos = atomicAdd(&base[id], 1);
    meta[META_SLIST + pos] = tid;
}

// ---------------- K2: fc1 partial GEMM, grid (task, htile, ksplit) ----------------
// v5: same single-reader structure as v4 (FETCH was already minimal = 64 MB),
// but sized to the TRUE distribution (T=64 live tasks, n_bar=16):
//   - SMAX 64->32: acc[8] (32 VGPR) instead of acc[16] (64), slots mostly live
//   - __launch_bounds__(256,4): cap at 128 VGPR -> NO scratch spill (v4 at 256
//     VGPR spilled: WRITE_SIZE 78.8 MB vs 8 MB actually written), 2 blocks/CU
// Per-(sample,col) fmaf chain: d ascending within the ksp slice -> hpre
// bit-identical (chunk partition does not change the linear chain order).
template <int KSP>
__global__ __launch_bounds__(256, 4) void fc1_kernel(const float* __restrict__ xs,
                                                     const float* __restrict__ w1,
                                                     const int* __restrict__ meta,
                                                     float* __restrict__ hpre) {
    constexpr int DK = D_DIM / KSP;      // 128 for KSP=4
    constexpr int NCHUNK = DK / 8;
    int task  = blockIdx.x;
    int htile = blockIdx.y;
    int ksp   = blockIdx.z;
    int tid   = threadIdx.x;
    int lane  = tid & 63;
    int wv4   = tid >> 6;

    int off0 = meta[META_OFF + task];
    int n    = meta[META_OFF + task + 1] - off0;
    if (n == 0) return;

    const int* slist = meta + META_SLIST + off0;

    __shared__ __align__(16) float xlds[SMAX][DK];   // 16 KB at KSP=4

    int hbase = htile * HTILE + lane * 4;
    int d0    = ksp * DK;
    const float* wbase = w1 + ((size_t)task * D_DIM + d0) * H_DIM + hbase;
    float* hout = hpre + (size_t)ksp * ((size_t)B_N * H_DIM);

    for (int sbase = 0; sbase < n; sbase += SMAX) {
        int ns = min(SMAX, n - sbase);

        // stage xs rows (coalesced float4)
        for (int idx = tid; idx < SMAX * (DK / 4); idx += 256) {
            int sl = idx / (DK / 4);
            int f  = idx - sl * (DK / 4);
            if (sl < ns) {
                int smp = slist[sbase + sl];
                *(float4*)(&xlds[sl][4 * f]) =
                    *(const float4*)(xs + (size_t)smp * D_DIM + d0 + 4 * f);
            }
        }
        __syncthreads();

        float4 acc[SMAX / 4];                        // 8 x float4 = 32 VGPR
#pragma unroll
        for (int j = 0; j < SMAX / 4; ++j) acc[j] = make_float4(0.f, 0.f, 0.f, 0.f);

        float4 wva[8], wvb[8];

#define LOADW(buf, cc)                                                        \
        _Pragma("unroll")                                                     \
        for (int u = 0; u < 8; ++u)                                           \
            buf[u] = *(const float4*)(wbase + (size_t)((cc) * 8 + u) * H_DIM);

#define COMPW(buf, cc) do {                                                   \
        _Pragma("unroll")                                                     \
        for (int j = 0; j < SMAX / 4; ++j) {                                  \
            int sl = wv4 + 4 * j;                                             \
            if (sl < ns) {                 /* wave-uniform predicate */       \
                const float* xp = &xlds[sl][8 * (cc)];                        \
                float4 xa = *(const float4*)xp;                               \
                float4 xb = *(const float4*)(xp + 4);                         \
                float xv[8] = {xa.x, xa.y, xa.z, xa.w,                        \
                               xb.x, xb.y, xb.z, xb.w};                       \
                _Pragma("unroll")                                             \
                for (int u = 0; u < 8; ++u) {                                 \
                    acc[j].x = fmaf(xv[u], buf[u].x, acc[j].x);               \
                    acc[j].y = fmaf(xv[u], buf[u].y, acc[j].y);               \
                    acc[j].z = fmaf(xv[u], buf[u].z, acc[j].z);               \
                    acc[j].w = fmaf(xv[u], buf[u].w, acc[j].w);               \
                }                                                             \
            }                                                                 \
        }                                                                     \
    } while (0)

        LOADW(wva, 0);
#pragma unroll
        for (int c = 0; c < NCHUNK; ++c) {
            if ((c & 1) == 0) {
                if (c + 1 < NCHUNK) { LOADW(wvb, c + 1); }
                COMPW(wva, c);
            } else {
                if (c + 1 < NCHUNK) { LOADW(wva, c + 1); }
                COMPW(wvb, c);
            }
        }
#undef LOADW
#undef COMPW

#pragma unroll
        for (int j = 0; j < SMAX / 4; ++j) {
            int sl = wv4 + 4 * j;
            if (sl < ns) {
                int smp = slist[sbase + sl];
                *(float4*)(hout + (size_t)smp * H_DIM + hbase) = acc[j];
            }
        }
        __syncthreads();
    }
}

// ---------------- threefry2x32, partitionable counter mode, key = (0, 1) --------
// (validated bit-exact — do not touch)
__device__ __forceinline__ uint32_t rotl32(uint32_t x, int r) {
    return (x << r) | (x >> (32 - r));
}

__device__ __forceinline__ uint32_t threefry_bits_part(uint32_t i) {
    uint32_t x0 = 0u;        // i >> 32 for i < 2^32
    uint32_t x1 = i;
    const uint32_t ks0 = 0u, ks1 = 1u, ks2 = 0x1BD11BDAu ^ 0u ^ 1u;
    x0 += ks0; x1 += ks1;
#define TFR(r) { x0 += x1; x1 = rotl32(x1, (r)); x1 ^= x0; }
    TFR(13) TFR(15) TFR(26) TFR(6)
    x0 += ks1; x1 += ks2 + 1u;
    TFR(17) TFR(29) TFR(16) TFR(24)
    x0 += ks2; x1 += ks0 + 2u;
    TFR(13) TFR(15) TFR(26) TFR(6)
    x0 += ks0; x1 += ks1 + 3u;
    TFR(17) TFR(29) TFR(16) TFR(24)
    x0 += ks1; x1 += ks2 + 4u;
    TFR(13) TFR(15) TFR(26) TFR(6)
    x0 += ks2; x1 += ks0 + 5u;
#undef TFR
    return x0 ^ x1;
}

// ---------------- K3: relu + fc2 + log_softmax + gumbel sample ----
// (validated rounds 3/4, absmax 0.0 — unchanged)
template <int KSP>
__global__ __launch_bounds__(256) void head_kernel(const int* __restrict__ meta,
                                                   const float* __restrict__ hpre,
                                                   const float* __restrict__ b1,
                                                   const float* __restrict__ w2,
                                                   const float* __restrict__ b2,
                                                   float* __restrict__ out) {
    __shared__ __align__(16) float w2l[H_DIM * A_DIM];   // 36 KB
    __shared__ float red[4][16][A_DIM];
    __shared__ float logits_lds[4][A_DIM];

    int t    = blockIdx.x;
    int y    = blockIdx.y;
    int tid  = threadIdx.x;
    int lane = tid & 63;
    int wv   = tid >> 6;

    int off0 = meta[META_OFF + t];
    int n    = meta[META_OFF + t + 1] - off0;
    if (4 * y >= n) return;                      // uniform block exit
    int K = (n - 4 * y - 1) / 32 + 1;            // uniform rounds per block

    const int* slist = meta + META_SLIST + off0;

    // ---- stage w2[t] into LDS, coalesced: 2304 float4 over 256 threads ----
    const float4* g4 = (const float4*)(w2 + (size_t)t * (H_DIM * A_DIM));
    float4* l4 = (float4*)w2l;
#pragma unroll
    for (int i = 0; i < (H_DIM * A_DIM) / (256 * 4); ++i)   // 9 iters
        l4[i * 256 + tid] = g4[i * 256 + tid];
    __syncthreads();

    for (int rnd = 0; rnd < K; ++rnd) {
        int slot = 4 * y + wv + 32 * rnd;
        bool active = slot < n;
        int s = active ? slist[slot] : 0;

        // ---- h = relu(sum_k partial_k + b1) ----
        float hreg[H_DIM / 64];
#pragma unroll
        for (int kk = 0; kk < H_DIM / 64; ++kk) {
            int h = lane + 64 * kk;
            size_t p = (size_t)s * H_DIM + h;
            float v = b1[(size_t)t * H_DIM + h];
#pragma unroll
            for (int q = 0; q < KSP; ++q)
                v += hpre[(size_t)q * ((size_t)B_N * H_DIM) + p];
            hreg[kk] = fmaxf(v, 0.f);
        }

        // ---- per-lane partial logits from LDS ----
        float la[A_DIM];
#pragma unroll
        for (int a = 0; a < A_DIM; ++a) la[a] = 0.f;
#pragma unroll
        for (int kk = 0; kk < H_DIM / 64; ++kk) {
            int h = lane + 64 * kk;
            const float2* row = (const float2*)&w2l[h * A_DIM];
            float hk = hreg[kk];
#pragma unroll
            for (int a2 = 0; a2 < A_DIM / 2; ++a2) {
                float2 ww = row[a2];
                la[2 * a2]     = fmaf(hk, ww.x, la[2 * a2]);
                la[2 * a2 + 1] = fmaf(hk, ww.y, la[2 * a2 + 1]);
            }
        }

        // ---- reduce 64 partials: shfl_xor(1,2) -> 16 rows -> LDS -> 18-lane sum ----
#pragma unroll
        for (int a = 0; a < A_DIM; ++a) {
            la[a] += __shfl_xor(la[a], 1);
            la[a] += __shfl_xor(la[a], 2);
        }
        if ((lane & 3) == 0) {
            int g = lane >> 2;
#pragma unroll
            for (int a = 0; a < A_DIM; ++a) red[wv][g][a] = la[a];
        }
        __syncthreads();
        if (lane < A_DIM) {
            float sum = b2[(size_t)t * A_DIM + lane];
#pragma unroll
            for (int g = 0; g < 16; ++g) sum += red[wv][g][lane];
            logits_lds[wv][lane] = sum;
        }
        __syncthreads();

        // ---- tail: identical to the validated code ----
        float lg = (lane < A_DIM) ? logits_lds[wv][lane] : -INFINITY;

        float z = -INFINITY;
        if (lane < A_DIM) {
            uint32_t bits = threefry_bits_part((uint32_t)(s * A_DIM + lane));
            float f = __uint_as_float(0x3f800000u | (bits >> 9)) - 1.0f;
            float u = fmaxf(f, 1.17549435e-38f);   // jnp.finfo(f32).tiny
            float g = -logf(-logf(u));
            z = lg + g;
        }
        int idx = lane;
#pragma unroll
        for (int o = 1; o < 64; o <<= 1) {
            float oz = __shfl_xor(z, o);
            int   oi = __shfl_xor(idx, o);
            if (oz > z || (oz == z && oi < idx)) { z = oz; idx = oi; }
        }

        float mx = lg;
#pragma unroll
        for (int o = 1; o < 64; o <<= 1) mx = fmaxf(mx, __shfl_xor(mx, o));
        float e = (lane < A_DIM) ? expf(lg - mx) : 0.f;
#pragma unroll
        for (int o = 1; o < 64; o <<= 1) e += __shfl_xor(e, o);
        float lse = mx + logf(e);
        float lp = lg - lse;
        float c = (lane < A_DIM) ? expf(lp) * lp : 0.f;
#pragma unroll
        for (int o = 1; o < 64; o <<= 1) c += __shfl_xor(c, o);

        if (active && lane == 0) {
            out[s]             = (float)idx;                 // action
            out[B_N + s]       = logits_lds[wv][idx] - lse;  // log_prob
            out[2 * B_N + s]   = -c;                         // entropy
        }
        __syncthreads();   // logits/red reuse next round (uniform: K is block-uniform)
    }
}

extern "C" void kernel_launch(void* const* d_in, const int* in_sizes, int n_in,
                              void* d_out, int out_size, void* d_ws, size_t ws_size,
                              hipStream_t stream) {
    const float* xs      = (const float*)d_in[0];
    const int*   traw    = (const int*)d_in[1];   // int32 or int64 — detected on device
    const float* w1      = (const float*)d_in[2];
    const float* b1      = (const float*)d_in[3];
    const float* w2      = (const float*)d_in[4];
    const float* b2      = (const float*)d_in[5];
    float* out = (float*)d_out;
    char*  ws  = (char*)d_ws;

    const size_t meta_bytes = META_INTS * sizeof(int);               // 8 KB
    const size_t part_bytes = (size_t)B_N * H_DIM * sizeof(float);   // 2 MB per K-split partial

    int ksp = 4;
    if (ws_size < meta_bytes + 4 * part_bytes) ksp = 2;
    if (ws_size < meta_bytes + 2 * part_bytes) ksp = 1;

    int*   meta = (int*)ws;
    float* hpre = (float*)(ws + meta_bytes);

    bucket_kernel<<<1, 1024, 0, stream>>>(traw, meta);

    if (ksp == 4) {
        fc1_kernel<4><<<dim3(T_N, 2, 4), 256, 0, stream>>>(xs, w1, meta, hpre);
        head_kernel<4><<<dim3(T_N, NSB2), 256, 0, stream>>>(meta, hpre, b1, w2, b2, out);
    } else if (ksp == 2) {
        fc1_kernel<2><<<dim3(T_N, 2, 2), 256, 0, stream>>>(xs, w1, meta, hpre);
        head_kernel<2><<<dim3(T_N, NSB2), 256, 0, stream>>>(meta, hpre, b1, w2, b2, out);
    } else {
        fc1_kernel<1><<<dim3(T_N, 2, 1), 256, 0, stream>>>(xs, w1, meta, hpre);
        head_kernel<1><<<dim3(T_N, NSB2), 256, 0, stream>>>(meta, hpre, b1, w2, b2, out);
    }
}

// Round 6
// 128.498 us; speedup vs baseline: 3.2099x; 3.2099x over previous
//
#include <hip/hip_runtime.h>
#include <stdint.h>

#define B_N   1024
#define D_DIM 512
#define H_DIM 512
#define A_DIM 18
#define T_N   64
#define HTILE 256
#define SMAX  32      // sample slots per fc1 block pass (n_bar=16 -> one pass)
#define NSB2  8       // head sample-blocks per task

// meta workspace layout (ints): off[0..64] at META_OFF, slist[1024] at META_SLIST
#define META_OFF   0
#define META_SLIST 256
#define META_INTS  2048      // 8 KB reserved before hpre

// Inline task_id dtype detection (int32 vs int64), executed by one full wave.
__device__ __forceinline__ bool taskid_is_int32(const int* raw, int lane) {
    int probe = raw[lane];
    unsigned long long odd = __ballot((lane & 1) && probe != 0);
    return odd != 0ull;
}

// ---------------- K0: bucket task ids once (1 block, 1024 threads) ----------------
// (validated rounds 3-5, absmax 0.0 — unchanged)
__global__ __launch_bounds__(1024) void bucket_kernel(const int* __restrict__ raw,
                                                      int* __restrict__ meta) {
    __shared__ int cnt[T_N];
    __shared__ int base[T_N];
    __shared__ int flag32;
    int tid = threadIdx.x;
    if (tid < 64) {
        bool is32 = taskid_is_int32(raw, tid);
        if (tid == 0) flag32 = is32 ? 1 : 0;
    }
    if (tid < T_N) cnt[tid] = 0;
    __syncthreads();
    int id = flag32 ? raw[tid] : raw[2 * tid];
    atomicAdd(&cnt[id], 1);
    __syncthreads();
    if (tid < 64) {
        int v = cnt[tid];
        int x = v;
#pragma unroll
        for (int o = 1; o < 64; o <<= 1) {          // inclusive scan, wave 0
            int tv = __shfl_up(x, o);
            if (tid >= o) x += tv;
        }
        int excl = x - v;
        meta[META_OFF + tid] = excl;
        base[tid] = excl;
        if (tid == 63) meta[META_OFF + 64] = x;     // = B_N
    }
    __syncthreads();
    int pos = atomicAdd(&base[id], 1);
    meta[META_SLIST + pos] = tid;
}

// ---------------- K2: fc1 partial GEMM, grid (task, htile, ksplit) ----------------
// v6 = the round-0 PROVEN register configuration (single-buffered wvr[8] float4,
// acc[8] float4, slot-per-wave split: VGPR ~236, WRITE_SIZE exactly 8 MB = no
// spill, fc1 <= 40 us) with two strictly-cheaper changes:
//   - per-block task-id re-scan replaced by the bucketed meta read (K0)
//   - n_bar = 16 <= SMAX = 32 -> single pass (no double tile stream)
// NO register double-buffer, NO launch-bounds cap (v4/v5 post-mortem: every
// variant that added them spilled: WRITE 78-248 MB vs 8 MB real).
// Per-(sample,col) fmaf chain: d ascending within the ksp slice, same xv order
// as all validated versions -> hpre bit-identical.
template <int KSP>
__global__ __launch_bounds__(256) void fc1_kernel(const float* __restrict__ xs,
                                                  const float* __restrict__ w1,
                                                  const int* __restrict__ meta,
                                                  float* __restrict__ hpre) {
    constexpr int DK = D_DIM / KSP;      // 128 for KSP=4
    int task  = blockIdx.x;
    int htile = blockIdx.y;
    int ksp   = blockIdx.z;
    int tid   = threadIdx.x;
    int lane  = tid & 63;
    int wv4   = tid >> 6;

    int off0 = meta[META_OFF + task];
    int n    = meta[META_OFF + task + 1] - off0;
    if (n == 0) return;

    const int* slist = meta + META_SLIST + off0;

    __shared__ __align__(16) float xlds[SMAX][DK];   // 16 KB at KSP=4

    int hbase = htile * HTILE + lane * 4;
    int d0    = ksp * DK;
    const float* wbase = w1 + ((size_t)task * D_DIM + d0) * H_DIM + hbase;
    float* hout = hpre + (size_t)ksp * ((size_t)B_N * H_DIM);

    for (int sbase = 0; sbase < n; sbase += SMAX) {
        int ns = min(SMAX, n - sbase);

        // stage xs rows (coalesced float4)
        for (int idx = tid; idx < SMAX * (DK / 4); idx += 256) {
            int sl = idx / (DK / 4);
            int f  = idx - sl * (DK / 4);
            if (sl < ns) {
                int smp = slist[sbase + sl];
                *(float4*)(&xlds[sl][4 * f]) =
                    *(const float4*)(xs + (size_t)smp * D_DIM + d0 + 4 * f);
            }
        }
        __syncthreads();

        float4 acc[SMAX / 4];                        // 8 x float4 = 32 VGPR
#pragma unroll
        for (int j = 0; j < SMAX / 4; ++j) acc[j] = make_float4(0.f, 0.f, 0.f, 0.f);

        for (int d = 0; d < DK; d += 8) {
            float4 wvr[8];
#pragma unroll
            for (int u = 0; u < 8; ++u)
                wvr[u] = *(const float4*)(wbase + (size_t)(d + u) * H_DIM);
#pragma unroll
            for (int j = 0; j < SMAX / 4; ++j) {
                int sl = wv4 + 4 * j;
                if (sl < ns) {                    // wave-uniform predicate (wv4 per-wave)
                    const float* xp = &xlds[sl][d];
                    float4 xa = *(const float4*)xp;
                    float4 xb = *(const float4*)(xp + 4);
                    float xv[8] = {xa.x, xa.y, xa.z, xa.w, xb.x, xb.y, xb.z, xb.w};
#pragma unroll
                    for (int u = 0; u < 8; ++u) {
                        acc[j].x = fmaf(xv[u], wvr[u].x, acc[j].x);
                        acc[j].y = fmaf(xv[u], wvr[u].y, acc[j].y);
                        acc[j].z = fmaf(xv[u], wvr[u].z, acc[j].z);
                        acc[j].w = fmaf(xv[u], wvr[u].w, acc[j].w);
                    }
                }
            }
        }

#pragma unroll
        for (int j = 0; j < SMAX / 4; ++j) {
            int sl = wv4 + 4 * j;
            if (sl < ns) {
                int smp = slist[sbase + sl];
                *(float4*)(hout + (size_t)smp * H_DIM + hbase) = acc[j];
            }
        }
        __syncthreads();
    }
}

// ---------------- threefry2x32, partitionable counter mode, key = (0, 1) --------
// (validated bit-exact — do not touch)
__device__ __forceinline__ uint32_t rotl32(uint32_t x, int r) {
    return (x << r) | (x >> (32 - r));
}

__device__ __forceinline__ uint32_t threefry_bits_part(uint32_t i) {
    uint32_t x0 = 0u;        // i >> 32 for i < 2^32
    uint32_t x1 = i;
    const uint32_t ks0 = 0u, ks1 = 1u, ks2 = 0x1BD11BDAu ^ 0u ^ 1u;
    x0 += ks0; x1 += ks1;
#define TFR(r) { x0 += x1; x1 = rotl32(x1, (r)); x1 ^= x0; }
    TFR(13) TFR(15) TFR(26) TFR(6)
    x0 += ks1; x1 += ks2 + 1u;
    TFR(17) TFR(29) TFR(16) TFR(24)
    x0 += ks2; x1 += ks0 + 2u;
    TFR(13) TFR(15) TFR(26) TFR(6)
    x0 += ks0; x1 += ks1 + 3u;
    TFR(17) TFR(29) TFR(16) TFR(24)
    x0 += ks1; x1 += ks2 + 4u;
    TFR(13) TFR(15) TFR(26) TFR(6)
    x0 += ks2; x1 += ks0 + 5u;
#undef TFR
    return x0 ^ x1;
}

// ---------------- K3: relu + fc2 + log_softmax + gumbel sample ----
// (validated rounds 3-5, absmax 0.0 — unchanged)
template <int KSP>
__global__ __launch_bounds__(256) void head_kernel(const int* __restrict__ meta,
                                                   const float* __restrict__ hpre,
                                                   const float* __restrict__ b1,
                                                   const float* __restrict__ w2,
                                                   const float* __restrict__ b2,
                                                   float* __restrict__ out) {
    __shared__ __align__(16) float w2l[H_DIM * A_DIM];   // 36 KB
    __shared__ float red[4][16][A_DIM];
    __shared__ float logits_lds[4][A_DIM];

    int t    = blockIdx.x;
    int y    = blockIdx.y;
    int tid  = threadIdx.x;
    int lane = tid & 63;
    int wv   = tid >> 6;

    int off0 = meta[META_OFF + t];
    int n    = meta[META_OFF + t + 1] - off0;
    if (4 * y >= n) return;                      // uniform block exit
    int K = (n - 4 * y - 1) / 32 + 1;            // uniform rounds per block

    const int* slist = meta + META_SLIST + off0;

    // ---- stage w2[t] into LDS, coalesced: 2304 float4 over 256 threads ----
    const float4* g4 = (const float4*)(w2 + (size_t)t * (H_DIM * A_DIM));
    float4* l4 = (float4*)w2l;
#pragma unroll
    for (int i = 0; i < (H_DIM * A_DIM) / (256 * 4); ++i)   // 9 iters
        l4[i * 256 + tid] = g4[i * 256 + tid];
    __syncthreads();

    for (int rnd = 0; rnd < K; ++rnd) {
        int slot = 4 * y + wv + 32 * rnd;
        bool active = slot < n;
        int s = active ? slist[slot] : 0;

        // ---- h = relu(sum_k partial_k + b1) ----
        float hreg[H_DIM / 64];
#pragma unroll
        for (int kk = 0; kk < H_DIM / 64; ++kk) {
            int h = lane + 64 * kk;
            size_t p = (size_t)s * H_DIM + h;
            float v = b1[(size_t)t * H_DIM + h];
#pragma unroll
            for (int q = 0; q < KSP; ++q)
                v += hpre[(size_t)q * ((size_t)B_N * H_DIM) + p];
            hreg[kk] = fmaxf(v, 0.f);
        }

        // ---- per-lane partial logits from LDS ----
        float la[A_DIM];
#pragma unroll
        for (int a = 0; a < A_DIM; ++a) la[a] = 0.f;
#pragma unroll
        for (int kk = 0; kk < H_DIM / 64; ++kk) {
            int h = lane + 64 * kk;
            const float2* row = (const float2*)&w2l[h * A_DIM];
            float hk = hreg[kk];
#pragma unroll
            for (int a2 = 0; a2 < A_DIM / 2; ++a2) {
                float2 ww = row[a2];
                la[2 * a2]     = fmaf(hk, ww.x, la[2 * a2]);
                la[2 * a2 + 1] = fmaf(hk, ww.y, la[2 * a2 + 1]);
            }
        }

        // ---- reduce 64 partials: shfl_xor(1,2) -> 16 rows -> LDS -> 18-lane sum ----
#pragma unroll
        for (int a = 0; a < A_DIM; ++a) {
            la[a] += __shfl_xor(la[a], 1);
            la[a] += __shfl_xor(la[a], 2);
        }
        if ((lane & 3) == 0) {
            int g = lane >> 2;
#pragma unroll
            for (int a = 0; a < A_DIM; ++a) red[wv][g][a] = la[a];
        }
        __syncthreads();
        if (lane < A_DIM) {
            float sum = b2[(size_t)t * A_DIM + lane];
#pragma unroll
            for (int g = 0; g < 16; ++g) sum += red[wv][g][lane];
            logits_lds[wv][lane] = sum;
        }
        __syncthreads();

        // ---- tail: identical to the validated code ----
        float lg = (lane < A_DIM) ? logits_lds[wv][lane] : -INFINITY;

        float z = -INFINITY;
        if (lane < A_DIM) {
            uint32_t bits = threefry_bits_part((uint32_t)(s * A_DIM + lane));
            float f = __uint_as_float(0x3f800000u | (bits >> 9)) - 1.0f;
            float u = fmaxf(f, 1.17549435e-38f);   // jnp.finfo(f32).tiny
            float g = -logf(-logf(u));
            z = lg + g;
        }
        int idx = lane;
#pragma unroll
        for (int o = 1; o < 64; o <<= 1) {
            float oz = __shfl_xor(z, o);
            int   oi = __shfl_xor(idx, o);
            if (oz > z || (oz == z && oi < idx)) { z = oz; idx = oi; }
        }

        float mx = lg;
#pragma unroll
        for (int o = 1; o < 64; o <<= 1) mx = fmaxf(mx, __shfl_xor(mx, o));
        float e = (lane < A_DIM) ? expf(lg - mx) : 0.f;
#pragma unroll
        for (int o = 1; o < 64; o <<= 1) e += __shfl_xor(e, o);
        float lse = mx + logf(e);
        float lp = lg - lse;
        float c = (lane < A_DIM) ? expf(lp) * lp : 0.f;
#pragma unroll
        for (int o = 1; o < 64; o <<= 1) c += __shfl_xor(c, o);

        if (active && lane == 0) {
            out[s]             = (float)idx;                 // action
            out[B_N + s]       = logits_lds[wv][idx] - lse;  // log_prob
            out[2 * B_N + s]   = -c;                         // entropy
        }
        __syncthreads();   // logits/red reuse next round (uniform: K is block-uniform)
    }
}

extern "C" void kernel_launch(void* const* d_in, const int* in_sizes, int n_in,
                              void* d_out, int out_size, void* d_ws, size_t ws_size,
                              hipStream_t stream) {
    const float* xs      = (const float*)d_in[0];
    const int*   traw    = (const int*)d_in[1];   // int32 or int64 — detected on device
    const float* w1      = (const float*)d_in[2];
    const float* b1      = (const float*)d_in[3];
    const float* w2      = (const float*)d_in[4];
    const float* b2      = (const float*)d_in[5];
    float* out = (float*)d_out;
    char*  ws  = (char*)d_ws;

    const size_t meta_bytes = META_INTS * sizeof(int);               // 8 KB
    const size_t part_bytes = (size_t)B_N * H_DIM * sizeof(float);   // 2 MB per K-split partial

    int ksp = 4;
    if (ws_size < meta_bytes + 4 * part_bytes) ksp = 2;
    if (ws_size < meta_bytes + 2 * part_bytes) ksp = 1;

    int*   meta = (int*)ws;
    float* hpre = (float*)(ws + meta_bytes);

    bucket_kernel<<<1, 1024, 0, stream>>>(traw, meta);

    if (ksp == 4) {
        fc1_kernel<4><<<dim3(T_N, 2, 4), 256, 0, stream>>>(xs, w1, meta, hpre);
        head_kernel<4><<<dim3(T_N, NSB2), 256, 0, stream>>>(meta, hpre, b1, w2, b2, out);
    } else if (ksp == 2) {
        fc1_kernel<2><<<dim3(T_N, 2, 2), 256, 0, stream>>>(xs, w1, meta, hpre);
        head_kernel<2><<<dim3(T_N, NSB2), 256, 0, stream>>>(meta, hpre, b1, w2, b2, out);
    } else {
        fc1_kernel<1><<<dim3(T_N, 2, 1), 256, 0, stream>>>(xs, w1, meta, hpre);
        head_kernel<1><<<dim3(T_N, NSB2), 256, 0, stream>>>(meta, hpre, b1, w2, b2, out);
    }
}

// Round 7
// 125.366 us; speedup vs baseline: 3.2901x; 1.0250x over previous
//
#include <hip/hip_runtime.h>
#include <stdint.h>

#define B_N   1024
#define D_DIM 512
#define H_DIM 512
#define A_DIM 18
#define T_N   64
#define HTILE 256
#define SMAX  32      // sample slots per fc1 block pass (n_bar=16 -> one pass)
#define NSB2  8       // head sample-blocks per task

// meta workspace layout (ints): off[0..64] at META_OFF, slist[1024] at META_SLIST
#define META_OFF   0
#define META_SLIST 256
#define META_INTS  2048      // 8 KB reserved before hpre

// Inline task_id dtype detection (int32 vs int64), executed by one full wave.
__device__ __forceinline__ bool taskid_is_int32(const int* raw, int lane) {
    int probe = raw[lane];
    unsigned long long odd = __ballot((lane & 1) && probe != 0);
    return odd != 0ull;
}

// ---------------- K0: bucket task ids once (1 block, 1024 threads) ----------------
// (validated rounds 3-6, absmax 0.0 — unchanged)
__global__ __launch_bounds__(1024) void bucket_kernel(const int* __restrict__ raw,
                                                      int* __restrict__ meta) {
    __shared__ int cnt[T_N];
    __shared__ int base[T_N];
    __shared__ int flag32;
    int tid = threadIdx.x;
    if (tid < 64) {
        bool is32 = taskid_is_int32(raw, tid);
        if (tid == 0) flag32 = is32 ? 1 : 0;
    }
    if (tid < T_N) cnt[tid] = 0;
    __syncthreads();
    int id = flag32 ? raw[tid] : raw[2 * tid];
    atomicAdd(&cnt[id], 1);
    __syncthreads();
    if (tid < 64) {
        int v = cnt[tid];
        int x = v;
#pragma unroll
        for (int o = 1; o < 64; o <<= 1) {          // inclusive scan, wave 0
            int tv = __shfl_up(x, o);
            if (tid >= o) x += tv;
        }
        int excl = x - v;
        meta[META_OFF + tid] = excl;
        base[tid] = excl;
        if (tid == 63) meta[META_OFF + 64] = x;     // = B_N
    }
    __syncthreads();
    int pos = atomicAdd(&base[id], 1);
    meta[META_SLIST + pos] = tid;
}

// ---------------- K2: fc1 partial GEMM, grid (task, htile, ksplit) ----------------
// v7: LDS-staged, double-buffered w tile. Rationale (r6 post-mortem): v6's four
// waves issued IDENTICAL single-buffered w loads and drained vmcnt every chunk
// (2 waves/SIMD -> no TLP to hide ~900cy); both earlier fixes (reg dbuf,
// col-owning) died by VGPR spill (WRITE_SIZE 78-248 MB vs 8 MB real).
// Here each thread stages only 2 float4 (8 VGPR): load chunk c+1 -> regs while
// computing chunk c from wlds[buf]; regs -> wlds[buf^1]; ONE barrier per chunk.
// Buffer-reuse safety: every wave's compute(c-1) precedes barrier(c) in program
// order, so writes at iter c+1 (other buffer) and reuse at c+2 are race-free.
// Compute inner loop is unchanged vs the validated v6 (same wvr values from
// LDS, same j/u fmaf order) -> hpre bit-identical.
template <int KSP>
__global__ __launch_bounds__(256) void fc1_kernel(const float* __restrict__ xs,
                                                  const float* __restrict__ w1,
                                                  const int* __restrict__ meta,
                                                  float* __restrict__ hpre) {
    constexpr int DK = D_DIM / KSP;      // 128 for KSP=4
    constexpr int NCHUNK = DK / 8;       // 16
    int task  = blockIdx.x;
    int htile = blockIdx.y;
    int ksp   = blockIdx.z;
    int tid   = threadIdx.x;
    int lane  = tid & 63;
    int wv4   = tid >> 6;

    int off0 = meta[META_OFF + task];
    int n    = meta[META_OFF + task + 1] - off0;
    if (n == 0) return;

    const int* slist = meta + META_SLIST + off0;

    __shared__ __align__(16) float xlds[SMAX][DK];        // 16 KB at KSP=4
    __shared__ __align__(16) float wlds[2][8][HTILE];     // 2 x 8 KB double buffer

    int hbase = htile * HTILE + lane * 4;
    int d0    = ksp * DK;
    const float* wtile = w1 + ((size_t)task * D_DIM + d0) * H_DIM + htile * HTILE;
    float* hout = hpre + (size_t)ksp * ((size_t)B_N * H_DIM);

    // staging map: float4 index i in [0,512) of an 8x256 chunk:
    // row = i>>6, colq = i&63. Thread t owns i = t and i = t+256.
    int r0row = tid >> 6;            // 0..3
    int r0col = (tid & 63) * 4;
    int r1row = 4 + (tid >> 6);      // 4..7
    int r1col = r0col;

#define WLOAD(cc, rrow, rcol) \
    (*(const float4*)(wtile + (size_t)((cc) * 8 + (rrow)) * H_DIM + (rcol)))

    for (int sbase = 0; sbase < n; sbase += SMAX) {
        int ns = min(SMAX, n - sbase);

        // stage xs rows (coalesced float4)
        for (int idx = tid; idx < SMAX * (DK / 4); idx += 256) {
            int sl = idx / (DK / 4);
            int f  = idx - sl * (DK / 4);
            if (sl < ns) {
                int smp = slist[sbase + sl];
                *(float4*)(&xlds[sl][4 * f]) =
                    *(const float4*)(xs + (size_t)smp * D_DIM + d0 + 4 * f);
            }
        }

        float4 acc[SMAX / 4];                        // 8 x float4 = 32 VGPR
#pragma unroll
        for (int j = 0; j < SMAX / 4; ++j) acc[j] = make_float4(0.f, 0.f, 0.f, 0.f);

        // prologue: chunk 0 -> staging regs
        float4 s0 = WLOAD(0, r0row, r0col);
        float4 s1 = WLOAD(0, r1row, r1col);
        __syncthreads();                             // xlds visible

        int buf = 0;
        for (int c = 0; c < NCHUNK; ++c) {
            // staged regs -> wlds[buf]
            *(float4*)(&wlds[buf][r0row][r0col]) = s0;
            *(float4*)(&wlds[buf][r1row][r1col]) = s1;
            if (c + 1 < NCHUNK) {                    // issue next chunk's loads
                s0 = WLOAD(c + 1, r0row, r0col);
                s1 = WLOAD(c + 1, r1row, r1col);
            }
            __syncthreads();                         // wlds[buf] visible

            // compute chunk c — identical fmaf order to validated v6
            float4 wvr[8];
#pragma unroll
            for (int u = 0; u < 8; ++u)
                wvr[u] = *(const float4*)(&wlds[buf][u][lane * 4]);
            int d = c * 8;
#pragma unroll
            for (int j = 0; j < SMAX / 4; ++j) {
                int sl = wv4 + 4 * j;
                if (sl < ns) {                    // wave-uniform predicate (wv4 per-wave)
                    const float* xp = &xlds[sl][d];
                    float4 xa = *(const float4*)xp;
                    float4 xb = *(const float4*)(xp + 4);
                    float xv[8] = {xa.x, xa.y, xa.z, xa.w, xb.x, xb.y, xb.z, xb.w};
#pragma unroll
                    for (int u = 0; u < 8; ++u) {
                        acc[j].x = fmaf(xv[u], wvr[u].x, acc[j].x);
                        acc[j].y = fmaf(xv[u], wvr[u].y, acc[j].y);
                        acc[j].z = fmaf(xv[u], wvr[u].z, acc[j].z);
                        acc[j].w = fmaf(xv[u], wvr[u].w, acc[j].w);
                    }
                }
            }
            buf ^= 1;
        }
#undef WLOAD

#pragma unroll
        for (int j = 0; j < SMAX / 4; ++j) {
            int sl = wv4 + 4 * j;
            if (sl < ns) {
                int smp = slist[sbase + sl];
                *(float4*)(hout + (size_t)smp * H_DIM + hbase) = acc[j];
            }
        }
        __syncthreads();                             // before next pass re-stages xlds
    }
}

// ---------------- threefry2x32, partitionable counter mode, key = (0, 1) --------
// (validated bit-exact — do not touch)
__device__ __forceinline__ uint32_t rotl32(uint32_t x, int r) {
    return (x << r) | (x >> (32 - r));
}

__device__ __forceinline__ uint32_t threefry_bits_part(uint32_t i) {
    uint32_t x0 = 0u;        // i >> 32 for i < 2^32
    uint32_t x1 = i;
    const uint32_t ks0 = 0u, ks1 = 1u, ks2 = 0x1BD11BDAu ^ 0u ^ 1u;
    x0 += ks0; x1 += ks1;
#define TFR(r) { x0 += x1; x1 = rotl32(x1, (r)); x1 ^= x0; }
    TFR(13) TFR(15) TFR(26) TFR(6)
    x0 += ks1; x1 += ks2 + 1u;
    TFR(17) TFR(29) TFR(16) TFR(24)
    x0 += ks2; x1 += ks0 + 2u;
    TFR(13) TFR(15) TFR(26) TFR(6)
    x0 += ks0; x1 += ks1 + 3u;
    TFR(17) TFR(29) TFR(16) TFR(24)
    x0 += ks1; x1 += ks2 + 4u;
    TFR(13) TFR(15) TFR(26) TFR(6)
    x0 += ks2; x1 += ks0 + 5u;
#undef TFR
    return x0 ^ x1;
}

// ---------------- K3: relu + fc2 + log_softmax + gumbel sample ----
// (validated rounds 3-6, absmax 0.0 — unchanged)
template <int KSP>
__global__ __launch_bounds__(256) void head_kernel(const int* __restrict__ meta,
                                                   const float* __restrict__ hpre,
                                                   const float* __restrict__ b1,
                                                   const float* __restrict__ w2,
                                                   const float* __restrict__ b2,
                                                   float* __restrict__ out) {
    __shared__ __align__(16) float w2l[H_DIM * A_DIM];   // 36 KB
    __shared__ float red[4][16][A_DIM];
    __shared__ float logits_lds[4][A_DIM];

    int t    = blockIdx.x;
    int y    = blockIdx.y;
    int tid  = threadIdx.x;
    int lane = tid & 63;
    int wv   = tid >> 6;

    int off0 = meta[META_OFF + t];
    int n    = meta[META_OFF + t + 1] - off0;
    if (4 * y >= n) return;                      // uniform block exit
    int K = (n - 4 * y - 1) / 32 + 1;            // uniform rounds per block

    const int* slist = meta + META_SLIST + off0;

    // ---- stage w2[t] into LDS, coalesced: 2304 float4 over 256 threads ----
    const float4* g4 = (const float4*)(w2 + (size_t)t * (H_DIM * A_DIM));
    float4* l4 = (float4*)w2l;
#pragma unroll
    for (int i = 0; i < (H_DIM * A_DIM) / (256 * 4); ++i)   // 9 iters
        l4[i * 256 + tid] = g4[i * 256 + tid];
    __syncthreads();

    for (int rnd = 0; rnd < K; ++rnd) {
        int slot = 4 * y + wv + 32 * rnd;
        bool active = slot < n;
        int s = active ? slist[slot] : 0;

        // ---- h = relu(sum_k partial_k + b1) ----
        float hreg[H_DIM / 64];
#pragma unroll
        for (int kk = 0; kk < H_DIM / 64; ++kk) {
            int h = lane + 64 * kk;
            size_t p = (size_t)s * H_DIM + h;
            float v = b1[(size_t)t * H_DIM + h];
#pragma unroll
            for (int q = 0; q < KSP; ++q)
                v += hpre[(size_t)q * ((size_t)B_N * H_DIM) + p];
            hreg[kk] = fmaxf(v, 0.f);
        }

        // ---- per-lane partial logits from LDS ----
        float la[A_DIM];
#pragma unroll
        for (int a = 0; a < A_DIM; ++a) la[a] = 0.f;
#pragma unroll
        for (int kk = 0; kk < H_DIM / 64; ++kk) {
            int h = lane + 64 * kk;
            const float2* row = (const float2*)&w2l[h * A_DIM];
            float hk = hreg[kk];
#pragma unroll
            for (int a2 = 0; a2 < A_DIM / 2; ++a2) {
                float2 ww = row[a2];
                la[2 * a2]     = fmaf(hk, ww.x, la[2 * a2]);
                la[2 * a2 + 1] = fmaf(hk, ww.y, la[2 * a2 + 1]);
            }
        }

        // ---- reduce 64 partials: shfl_xor(1,2) -> 16 rows -> LDS -> 18-lane sum ----
#pragma unroll
        for (int a = 0; a < A_DIM; ++a) {
            la[a] += __shfl_xor(la[a], 1);
            la[a] += __shfl_xor(la[a], 2);
        }
        if ((lane & 3) == 0) {
            int g = lane >> 2;
#pragma unroll
            for (int a = 0; a < A_DIM; ++a) red[wv][g][a] = la[a];
        }
        __syncthreads();
        if (lane < A_DIM) {
            float sum = b2[(size_t)t * A_DIM + lane];
#pragma unroll
            for (int g = 0; g < 16; ++g) sum += red[wv][g][lane];
            logits_lds[wv][lane] = sum;
        }
        __syncthreads();

        // ---- tail: identical to the validated code ----
        float lg = (lane < A_DIM) ? logits_lds[wv][lane] : -INFINITY;

        float z = -INFINITY;
        if (lane < A_DIM) {
            uint32_t bits = threefry_bits_part((uint32_t)(s * A_DIM + lane));
            float f = __uint_as_float(0x3f800000u | (bits >> 9)) - 1.0f;
            float u = fmaxf(f, 1.17549435e-38f);   // jnp.finfo(f32).tiny
            float g = -logf(-logf(u));
            z = lg + g;
        }
        int idx = lane;
#pragma unroll
        for (int o = 1; o < 64; o <<= 1) {
            float oz = __shfl_xor(z, o);
            int   oi = __shfl_xor(idx, o);
            if (oz > z || (oz == z && oi < idx)) { z = oz; idx = oi; }
        }

        float mx = lg;
#pragma unroll
        for (int o = 1; o < 64; o <<= 1) mx = fmaxf(mx, __shfl_xor(mx, o));
        float e = (lane < A_DIM) ? expf(lg - mx) : 0.f;
#pragma unroll
        for (int o = 1; o < 64; o <<= 1) e += __shfl_xor(e, o);
        float lse = mx + logf(e);
        float lp = lg - lse;
        float c = (lane < A_DIM) ? expf(lp) * lp : 0.f;
#pragma unroll
        for (int o = 1; o < 64; o <<= 1) c += __shfl_xor(c, o);

        if (active && lane == 0) {
            out[s]             = (float)idx;                 // action
            out[B_N + s]       = logits_lds[wv][idx] - lse;  // log_prob
            out[2 * B_N + s]   = -c;                         // entropy
        }
        __syncthreads();   // logits/red reuse next round (uniform: K is block-uniform)
    }
}

extern "C" void kernel_launch(void* const* d_in, const int* in_sizes, int n_in,
                              void* d_out, int out_size, void* d_ws, size_t ws_size,
                              hipStream_t stream) {
    const float* xs      = (const float*)d_in[0];
    const int*   traw    = (const int*)d_in[1];   // int32 or int64 — detected on device
    const float* w1      = (const float*)d_in[2];
    const float* b1      = (const float*)d_in[3];
    const float* w2      = (const float*)d_in[4];
    const float* b2      = (const float*)d_in[5];
    float* out = (float*)d_out;
    char*  ws  = (char*)d_ws;

    const size_t meta_bytes = META_INTS * sizeof(int);               // 8 KB
    const size_t part_bytes = (size_t)B_N * H_DIM * sizeof(float);   // 2 MB per K-split partial

    int ksp = 4;
    if (ws_size < meta_bytes + 4 * part_bytes) ksp = 2;
    if (ws_size < meta_bytes + 2 * part_bytes) ksp = 1;

    int*   meta = (int*)ws;
    float* hpre = (float*)(ws + meta_bytes);

    bucket_kernel<<<1, 1024, 0, stream>>>(traw, meta);

    if (ksp == 4) {
        fc1_kernel<4><<<dim3(T_N, 2, 4), 256, 0, stream>>>(xs, w1, meta, hpre);
        head_kernel<4><<<dim3(T_N, NSB2), 256, 0, stream>>>(meta, hpre, b1, w2, b2, out);
    } else if (ksp == 2) {
        fc1_kernel<2><<<dim3(T_N, 2, 2), 256, 0, stream>>>(xs, w1, meta, hpre);
        head_kernel<2><<<dim3(T_N, NSB2), 256, 0, stream>>>(meta, hpre, b1, w2, b2, out);
    } else {
        fc1_kernel<1><<<dim3(T_N, 2, 1), 256, 0, stream>>>(xs, w1, meta, hpre);
        head_kernel<1><<<dim3(T_N, NSB2), 256, 0, stream>>>(meta, hpre, b1, w2, b2, out);
    }
}

// Round 8
// 124.048 us; speedup vs baseline: 3.3250x; 1.0106x over previous
//
#include <hip/hip_runtime.h>
#include <stdint.h>

#define B_N   1024
#define D_DIM 512
#define H_DIM 512
#define A_DIM 18
#define T_N   64
#define HTILE 256
#define SMAX  32      // sample slots per fc1 block pass (n_bar=16 -> one pass)

// Inline task_id dtype detection (int32 vs int64), executed per-wave.
// Lanes read the first 64 int32 words (valid under both layouts). For int64
// data the odd words are zero high-words of values 0..63; for int32 data they
// are 32 random task ids (all-zero probability 64^-32 ~ 1e-58).
__device__ __forceinline__ bool taskid_is_int32(const int* raw, int lane) {
    int probe = raw[lane];
    unsigned long long odd = __ballot((lane & 1) && probe != 0);
    return odd != 0ull;
}

// ---------------- inline per-block bucketing (256 threads) ----------------
// Two-phase per-wave ballot scan of the 1024 task ids (4 KB, L2-resident).
// Wave wv owns ids [256*wv, 256*wv+256). Phase 1 counts, phase 2 compacts
// into slist (LDS). Slot order is irrelevant: every sample's computation is
// self-contained (hpre rows keyed by sample, threefry keyed by sample).
// Returns n. Caller must treat the two __syncthreads as block-uniform (they are).
__device__ __forceinline__ int build_slist(const int* __restrict__ raw, int task,
                                           int* slist, int* wcnt,
                                           int tid) {
    int lane = tid & 63;
    int wv   = tid >> 6;
    bool is32 = taskid_is_int32(raw, lane);

    int cnt = 0;
#pragma unroll
    for (int c = 0; c < 4; ++c) {
        int i  = 256 * wv + 64 * c + lane;
        int id = is32 ? raw[i] : raw[2 * i];
        cnt += __popcll(__ballot(id == task));   // lane-uniform within wave
    }
    if (lane == 0) wcnt[wv] = cnt;
    __syncthreads();
    int n = wcnt[0] + wcnt[1] + wcnt[2] + wcnt[3];
    int base = 0;
    for (int w = 0; w < wv; ++w) base += wcnt[w];   // wave-uniform prefix

#pragma unroll
    for (int c = 0; c < 4; ++c) {
        int i  = 256 * wv + 64 * c + lane;
        int id = is32 ? raw[i] : raw[2 * i];
        unsigned long long m = __ballot(id == task);
        if (id == task) {
            unsigned long long below = m & ((1ull << lane) - 1ull);
            slist[base + __popcll(below)] = i;
        }
        base += __popcll(m);
    }
    __syncthreads();
    return n;
}

// ---------------- K1: fc1 partial GEMM, grid (task, htile, ksplit) ----------------
// v8 = v7's proven LDS-dbuf core (no spill, absmax 0.0 in r7) with the bucket
// dispatch replaced by the inline scan above (removes 1 kernel + meta traffic).
// Per-(sample,col) fmaf chain identical to all validated versions -> hpre
// bit-identical.
template <int KSP>
__global__ __launch_bounds__(256) void fc1_kernel(const float* __restrict__ xs,
                                                  const float* __restrict__ w1,
                                                  const int* __restrict__ raw,
                                                  float* __restrict__ hpre) {
    constexpr int DK = D_DIM / KSP;      // 128 for KSP=4
    constexpr int NCHUNK = DK / 8;       // 16
    int task  = blockIdx.x;
    int htile = blockIdx.y;
    int ksp   = blockIdx.z;
    int tid   = threadIdx.x;
    int lane  = tid & 63;
    int wv4   = tid >> 6;

    __shared__ int slist[B_N];
    __shared__ int wcnt[4];
    __shared__ __align__(16) float xlds[SMAX][DK];        // 16 KB at KSP=4
    __shared__ __align__(16) float wlds[2][8][HTILE];     // 2 x 8 KB double buffer

    int n = build_slist(raw, task, slist, wcnt, tid);
    if (n == 0) return;

    int hbase = htile * HTILE + lane * 4;
    int d0    = ksp * DK;
    const float* wtile = w1 + ((size_t)task * D_DIM + d0) * H_DIM + htile * HTILE;
    float* hout = hpre + (size_t)ksp * ((size_t)B_N * H_DIM);

    // staging map: float4 index i in [0,512) of an 8x256 chunk:
    // row = i>>6, colq = i&63. Thread t owns i = t and i = t+256.
    int r0row = tid >> 6;            // 0..3
    int r0col = (tid & 63) * 4;
    int r1row = 4 + (tid >> 6);      // 4..7
    int r1col = r0col;

#define WLOAD(cc, rrow, rcol) \
    (*(const float4*)(wtile + (size_t)((cc) * 8 + (rrow)) * H_DIM + (rcol)))

    for (int sbase = 0; sbase < n; sbase += SMAX) {
        int ns = min(SMAX, n - sbase);

        // stage xs rows (coalesced float4)
        for (int idx = tid; idx < SMAX * (DK / 4); idx += 256) {
            int sl = idx / (DK / 4);
            int f  = idx - sl * (DK / 4);
            if (sl < ns) {
                int smp = slist[sbase + sl];
                *(float4*)(&xlds[sl][4 * f]) =
                    *(const float4*)(xs + (size_t)smp * D_DIM + d0 + 4 * f);
            }
        }

        float4 acc[SMAX / 4];                        // 8 x float4 = 32 VGPR
#pragma unroll
        for (int j = 0; j < SMAX / 4; ++j) acc[j] = make_float4(0.f, 0.f, 0.f, 0.f);

        // prologue: chunk 0 -> staging regs
        float4 s0 = WLOAD(0, r0row, r0col);
        float4 s1 = WLOAD(0, r1row, r1col);
        __syncthreads();                             // xlds visible

        int buf = 0;
        for (int c = 0; c < NCHUNK; ++c) {
            // staged regs -> wlds[buf]
            *(float4*)(&wlds[buf][r0row][r0col]) = s0;
            *(float4*)(&wlds[buf][r1row][r1col]) = s1;
            if (c + 1 < NCHUNK) {                    // issue next chunk's loads
                s0 = WLOAD(c + 1, r0row, r0col);
                s1 = WLOAD(c + 1, r1row, r1col);
            }
            __syncthreads();                         // wlds[buf] visible

            // compute chunk c — identical fmaf order to validated v6/v7
            float4 wvr[8];
#pragma unroll
            for (int u = 0; u < 8; ++u)
                wvr[u] = *(const float4*)(&wlds[buf][u][lane * 4]);
            int d = c * 8;
#pragma unroll
            for (int j = 0; j < SMAX / 4; ++j) {
                int sl = wv4 + 4 * j;
                if (sl < ns) {                    // wave-uniform predicate (wv4 per-wave)
                    const float* xp = &xlds[sl][d];
                    float4 xa = *(const float4*)xp;
                    float4 xb = *(const float4*)(xp + 4);
                    float xv[8] = {xa.x, xa.y, xa.z, xa.w, xb.x, xb.y, xb.z, xb.w};
#pragma unroll
                    for (int u = 0; u < 8; ++u) {
                        acc[j].x = fmaf(xv[u], wvr[u].x, acc[j].x);
                        acc[j].y = fmaf(xv[u], wvr[u].y, acc[j].y);
                        acc[j].z = fmaf(xv[u], wvr[u].z, acc[j].z);
                        acc[j].w = fmaf(xv[u], wvr[u].w, acc[j].w);
                    }
                }
            }
            buf ^= 1;
        }
#undef WLOAD

#pragma unroll
        for (int j = 0; j < SMAX / 4; ++j) {
            int sl = wv4 + 4 * j;
            if (sl < ns) {
                int smp = slist[sbase + sl];
                *(float4*)(hout + (size_t)smp * H_DIM + hbase) = acc[j];
            }
        }
        if (sbase + SMAX < n) __syncthreads();       // next pass re-stages xlds
    }
}

// ---------------- threefry2x32, partitionable counter mode, key = (0, 1) --------
// (validated bit-exact — do not touch)
__device__ __forceinline__ uint32_t rotl32(uint32_t x, int r) {
    return (x << r) | (x >> (32 - r));
}

__device__ __forceinline__ uint32_t threefry_bits_part(uint32_t i) {
    uint32_t x0 = 0u;        // i >> 32 for i < 2^32
    uint32_t x1 = i;
    const uint32_t ks0 = 0u, ks1 = 1u, ks2 = 0x1BD11BDAu ^ 0u ^ 1u;
    x0 += ks0; x1 += ks1;
#define TFR(r) { x0 += x1; x1 = rotl32(x1, (r)); x1 ^= x0; }
    TFR(13) TFR(15) TFR(26) TFR(6)
    x0 += ks1; x1 += ks2 + 1u;
    TFR(17) TFR(29) TFR(16) TFR(24)
    x0 += ks2; x1 += ks0 + 2u;
    TFR(13) TFR(15) TFR(26) TFR(6)
    x0 += ks0; x1 += ks1 + 3u;
    TFR(17) TFR(29) TFR(16) TFR(24)
    x0 += ks1; x1 += ks2 + 4u;
    TFR(13) TFR(15) TFR(26) TFR(6)
    x0 += ks2; x1 += ks0 + 5u;
#undef TFR
    return x0 ^ x1;
}

// ---------------- K2: relu + fc2 + log_softmax + gumbel sample ----
// v3: inline bucketing (no meta), grid (task, 4) with slot = 4y+wv+16*rnd
// (covers slots 0..31; halves the dead blocks of the old (task,8) map).
// Per-sample math byte-identical to the validated rounds 3-7 code.
template <int KSP>
__global__ __launch_bounds__(256) void head_kernel(const int* __restrict__ raw,
                                                   const float* __restrict__ hpre,
                                                   const float* __restrict__ b1,
                                                   const float* __restrict__ w2,
                                                   const float* __restrict__ b2,
                                                   float* __restrict__ out) {
    __shared__ int slist[B_N];
    __shared__ int wcnt[4];
    __shared__ __align__(16) float w2l[H_DIM * A_DIM];   // 36 KB
    __shared__ float red[4][16][A_DIM];
    __shared__ float logits_lds[4][A_DIM];

    int t    = blockIdx.x;
    int y    = blockIdx.y;
    int tid  = threadIdx.x;
    int lane = tid & 63;
    int wv   = tid >> 6;

    int n = build_slist(raw, t, slist, wcnt, tid);
    if (4 * y >= n) return;                      // uniform block exit
    int K = (n - 4 * y - 1) / 16 + 1;            // uniform rounds per block

    // ---- stage w2[t] into LDS, coalesced: 2304 float4 over 256 threads ----
    const float4* g4 = (const float4*)(w2 + (size_t)t * (H_DIM * A_DIM));
    float4* l4 = (float4*)w2l;
#pragma unroll
    for (int i = 0; i < (H_DIM * A_DIM) / (256 * 4); ++i)   // 9 iters
        l4[i * 256 + tid] = g4[i * 256 + tid];
    __syncthreads();

    for (int rnd = 0; rnd < K; ++rnd) {
        int slot = 4 * y + wv + 16 * rnd;
        bool active = slot < n;
        int s = active ? slist[slot] : 0;

        // ---- h = relu(sum_k partial_k + b1) ----
        float hreg[H_DIM / 64];
#pragma unroll
        for (int kk = 0; kk < H_DIM / 64; ++kk) {
            int h = lane + 64 * kk;
            size_t p = (size_t)s * H_DIM + h;
            float v = b1[(size_t)t * H_DIM + h];
#pragma unroll
            for (int q = 0; q < KSP; ++q)
                v += hpre[(size_t)q * ((size_t)B_N * H_DIM) + p];
            hreg[kk] = fmaxf(v, 0.f);
        }

        // ---- per-lane partial logits from LDS ----
        float la[A_DIM];
#pragma unroll
        for (int a = 0; a < A_DIM; ++a) la[a] = 0.f;
#pragma unroll
        for (int kk = 0; kk < H_DIM / 64; ++kk) {
            int h = lane + 64 * kk;
            const float2* row = (const float2*)&w2l[h * A_DIM];
            float hk = hreg[kk];
#pragma unroll
            for (int a2 = 0; a2 < A_DIM / 2; ++a2) {
                float2 ww = row[a2];
                la[2 * a2]     = fmaf(hk, ww.x, la[2 * a2]);
                la[2 * a2 + 1] = fmaf(hk, ww.y, la[2 * a2 + 1]);
            }
        }

        // ---- reduce 64 partials: shfl_xor(1,2) -> 16 rows -> LDS -> 18-lane sum ----
#pragma unroll
        for (int a = 0; a < A_DIM; ++a) {
            la[a] += __shfl_xor(la[a], 1);
            la[a] += __shfl_xor(la[a], 2);
        }
        if ((lane & 3) == 0) {
            int g = lane >> 2;
#pragma unroll
            for (int a = 0; a < A_DIM; ++a) red[wv][g][a] = la[a];
        }
        __syncthreads();
        if (lane < A_DIM) {
            float sum = b2[(size_t)t * A_DIM + lane];
#pragma unroll
            for (int g = 0; g < 16; ++g) sum += red[wv][g][lane];
            logits_lds[wv][lane] = sum;
        }
        __syncthreads();

        // ---- tail: identical to the validated code ----
        float lg = (lane < A_DIM) ? logits_lds[wv][lane] : -INFINITY;

        float z = -INFINITY;
        if (lane < A_DIM) {
            uint32_t bits = threefry_bits_part((uint32_t)(s * A_DIM + lane));
            float f = __uint_as_float(0x3f800000u | (bits >> 9)) - 1.0f;
            float u = fmaxf(f, 1.17549435e-38f);   // jnp.finfo(f32).tiny
            float g = -logf(-logf(u));
            z = lg + g;
        }
        int idx = lane;
#pragma unroll
        for (int o = 1; o < 64; o <<= 1) {
            float oz = __shfl_xor(z, o);
            int   oi = __shfl_xor(idx, o);
            if (oz > z || (oz == z && oi < idx)) { z = oz; idx = oi; }
        }

        float mx = lg;
#pragma unroll
        for (int o = 1; o < 64; o <<= 1) mx = fmaxf(mx, __shfl_xor(mx, o));
        float e = (lane < A_DIM) ? expf(lg - mx) : 0.f;
#pragma unroll
        for (int o = 1; o < 64; o <<= 1) e += __shfl_xor(e, o);
        float lse = mx + logf(e);
        float lp = lg - lse;
        float c = (lane < A_DIM) ? expf(lp) * lp : 0.f;
#pragma unroll
        for (int o = 1; o < 64; o <<= 1) c += __shfl_xor(c, o);

        if (active && lane == 0) {
            out[s]             = (float)idx;                 // action
            out[B_N + s]       = logits_lds[wv][idx] - lse;  // log_prob
            out[2 * B_N + s]   = -c;                         // entropy
        }
        __syncthreads();   // logits/red reuse next round (uniform: K is block-uniform)
    }
}

extern "C" void kernel_launch(void* const* d_in, const int* in_sizes, int n_in,
                              void* d_out, int out_size, void* d_ws, size_t ws_size,
                              hipStream_t stream) {
    const float* xs      = (const float*)d_in[0];
    const int*   traw    = (const int*)d_in[1];   // int32 or int64 — detected on device
    const float* w1      = (const float*)d_in[2];
    const float* b1      = (const float*)d_in[3];
    const float* w2      = (const float*)d_in[4];
    const float* b2      = (const float*)d_in[5];
    float* out = (float*)d_out;
    char*  ws  = (char*)d_ws;

    const size_t part_bytes = (size_t)B_N * H_DIM * sizeof(float);   // 2 MB per K-split partial

    int ksp = 4;
    if (ws_size < 4 * part_bytes) ksp = 2;
    if (ws_size < 2 * part_bytes) ksp = 1;

    float* hpre = (float*)ws;

    if (ksp == 4) {
        fc1_kernel<4><<<dim3(T_N, 2, 4), 256, 0, stream>>>(xs, w1, traw, hpre);
        head_kernel<4><<<dim3(T_N, 4), 256, 0, stream>>>(traw, hpre, b1, w2, b2, out);
    } else if (ksp == 2) {
        fc1_kernel<2><<<dim3(T_N, 2, 2), 256, 0, stream>>>(xs, w1, traw, hpre);
        head_kernel<2><<<dim3(T_N, 4), 256, 0, stream>>>(traw, hpre, b1, w2, b2, out);
    } else {
        fc1_kernel<1><<<dim3(T_N, 2, 1), 256, 0, stream>>>(xs, w1, traw, hpre);
        head_kernel<1><<<dim3(T_N, 4), 256, 0, stream>>>(traw, hpre, b1, w2, b2, out);
    }
}

// Round 9
// 123.054 us; speedup vs baseline: 3.3519x; 1.0081x over previous
//
#include <hip/hip_runtime.h>
#include <stdint.h>

#define B_N   1024
#define D_DIM 512
#define H_DIM 512
#define A_DIM 18
#define T_N   64
#define HTILE 256
#define SMAX  32      // sample slots per fc1 block pass (n_bar=16 -> one pass)

// Inline task_id dtype detection (int32 vs int64), executed per-wave.
// Lanes read the first 64 int32 words (valid under both layouts). For int64
// data the odd words are zero high-words of values 0..63; for int32 data they
// are 32 random task ids (all-zero probability 64^-32 ~ 1e-58).
__device__ __forceinline__ bool taskid_is_int32(const int* raw, int lane) {
    int probe = raw[lane];
    unsigned long long odd = __ballot((lane & 1) && probe != 0);
    return odd != 0ull;
}

// ---------------- inline per-block bucketing (256 threads) ----------------
// Two-phase per-wave ballot scan of the 1024 task ids (4 KB, L2-resident).
// Wave wv owns ids [256*wv, 256*wv+256). Phase 1 counts, phase 2 compacts
// into slist (LDS). Slot order is irrelevant: every sample's computation is
// self-contained (hpre rows keyed by sample, threefry keyed by sample).
__device__ __forceinline__ int build_slist(const int* __restrict__ raw, int task,
                                           int* slist, int* wcnt,
                                           int tid) {
    int lane = tid & 63;
    int wv   = tid >> 6;
    bool is32 = taskid_is_int32(raw, lane);

    int cnt = 0;
#pragma unroll
    for (int c = 0; c < 4; ++c) {
        int i  = 256 * wv + 64 * c + lane;
        int id = is32 ? raw[i] : raw[2 * i];
        cnt += __popcll(__ballot(id == task));   // lane-uniform within wave
    }
    if (lane == 0) wcnt[wv] = cnt;
    __syncthreads();
    int n = wcnt[0] + wcnt[1] + wcnt[2] + wcnt[3];
    int base = 0;
    for (int w = 0; w < wv; ++w) base += wcnt[w];   // wave-uniform prefix

#pragma unroll
    for (int c = 0; c < 4; ++c) {
        int i  = 256 * wv + 64 * c + lane;
        int id = is32 ? raw[i] : raw[2 * i];
        unsigned long long m = __ballot(id == task);
        if (id == task) {
            unsigned long long below = m & ((1ull << lane) - 1ull);
            slist[base + __popcll(below)] = i;
        }
        base += __popcll(m);
    }
    __syncthreads();
    return n;
}

// ---------------- K1: fc1 partial GEMM, grid (task, htile, ksplit) ----------------
// v9 = v8's LDS-dbuf core with the depth-0 pipeline fixed:
//  - per-chunk __syncthreads() (which forces s_waitcnt vmcnt(0) -> drains the
//    prefetch at EVERY barrier, serializing ~900cy HBM latency per chunk)
//    is replaced by {s_waitcnt lgkmcnt(0); s_barrier; sched_barrier(0)}.
//    LDS visibility is preserved; global loads stay in flight across barriers.
//  - depth-2 prefetch: two named staging reg pairs (sA/sB, static roles via
//    2-step unroll), so the ds_write of chunk c waits on loads issued two
//    chunks (~1000cy) earlier -> latency fully hidden.
// LDS double-buffer safety (1 barrier/chunk, unchanged): each wave's
// lgkmcnt(0) at barrier(c) covers its compute(c-1) ds_reads, so rewriting
// that buffer at c+1 is race-free.
// Per-(sample,col) fmaf chain identical to all validated versions -> hpre
// bit-identical.
template <int KSP>
__global__ __launch_bounds__(256) void fc1_kernel(const float* __restrict__ xs,
                                                  const float* __restrict__ w1,
                                                  const int* __restrict__ raw,
                                                  float* __restrict__ hpre) {
    constexpr int DK = D_DIM / KSP;      // 128 for KSP=4
    constexpr int NCHUNK = DK / 8;       // 16 (even -> 2-step unroll is exact)
    int task  = blockIdx.x;
    int htile = blockIdx.y;
    int ksp   = blockIdx.z;
    int tid   = threadIdx.x;
    int lane  = tid & 63;
    int wv4   = tid >> 6;

    __shared__ int slist[B_N];
    __shared__ int wcnt[4];
    __shared__ __align__(16) float xlds[SMAX][DK];        // 16 KB at KSP=4
    __shared__ __align__(16) float wlds[2][8][HTILE];     // 2 x 8 KB double buffer

    int n = build_slist(raw, task, slist, wcnt, tid);
    if (n == 0) return;

    int hbase = htile * HTILE + lane * 4;
    int d0    = ksp * DK;
    const float* wtile = w1 + ((size_t)task * D_DIM + d0) * H_DIM + htile * HTILE;
    float* hout = hpre + (size_t)ksp * ((size_t)B_N * H_DIM);

    // staging map: float4 index i in [0,512) of an 8x256 chunk:
    // row = i>>6, colq = i&63. Thread t owns i = t and i = t+256.
    int r0row = tid >> 6;            // 0..3
    int r0col = (tid & 63) * 4;
    int r1row = 4 + (tid >> 6);      // 4..7
    int r1col = r0col;

#define WLOAD(cc, rrow, rcol) \
    (*(const float4*)(wtile + (size_t)((cc) * 8 + (rrow)) * H_DIM + (rcol)))

    for (int sbase = 0; sbase < n; sbase += SMAX) {
        int ns = min(SMAX, n - sbase);

        // stage xs rows (coalesced float4)
        for (int idx = tid; idx < SMAX * (DK / 4); idx += 256) {
            int sl = idx / (DK / 4);
            int f  = idx - sl * (DK / 4);
            if (sl < ns) {
                int smp = slist[sbase + sl];
                *(float4*)(&xlds[sl][4 * f]) =
                    *(const float4*)(xs + (size_t)smp * D_DIM + d0 + 4 * f);
            }
        }

        float4 acc[SMAX / 4];                        // 8 x float4 = 32 VGPR
#pragma unroll
        for (int j = 0; j < SMAX / 4; ++j) acc[j] = make_float4(0.f, 0.f, 0.f, 0.f);

        // prologue: chunks 0,1 -> the two named staging pairs
        float4 sA0 = WLOAD(0, r0row, r0col);
        float4 sA1 = WLOAD(0, r1row, r1col);
        float4 sB0 = WLOAD(1, r0row, r0col);
        float4 sB1 = WLOAD(1, r1row, r1col);
        __syncthreads();                             // xlds visible (one-time full drain)

        int buf = 0;

        // one chunk step: write staged regs -> wlds[buf]; prefetch chunk CC+2
        // into the SAME reg pair; relaxed barrier; compute chunk CC.
#define WSTEP(R0, R1, CC) do {                                                \
        *(float4*)(&wlds[buf][r0row][r0col]) = R0;                            \
        *(float4*)(&wlds[buf][r1row][r1col]) = R1;                            \
        if ((CC) + 2 < NCHUNK) {                                              \
            R0 = WLOAD((CC) + 2, r0row, r0col);                               \
            R1 = WLOAD((CC) + 2, r1row, r1col);                               \
        }                                                                     \
        asm volatile("s_waitcnt lgkmcnt(0)" ::: "memory");                    \
        __builtin_amdgcn_s_barrier();                                         \
        __builtin_amdgcn_sched_barrier(0);                                    \
        {                                                                     \
            float4 wvr[8];                                                    \
            _Pragma("unroll")                                                 \
            for (int u = 0; u < 8; ++u)                                       \
                wvr[u] = *(const float4*)(&wlds[buf][u][lane * 4]);           \
            int d = (CC) * 8;                                                 \
            _Pragma("unroll")                                                 \
            for (int j = 0; j < SMAX / 4; ++j) {                              \
                int sl = wv4 + 4 * j;                                         \
                if (sl < ns) {               /* wave-uniform (wv4 per-wave) */\
                    const float* xp = &xlds[sl][d];                           \
                    float4 xa = *(const float4*)xp;                           \
                    float4 xb = *(const float4*)(xp + 4);                     \
                    float xv[8] = {xa.x, xa.y, xa.z, xa.w,                    \
                                   xb.x, xb.y, xb.z, xb.w};                   \
                    _Pragma("unroll")                                         \
                    for (int u = 0; u < 8; ++u) {                             \
                        acc[j].x = fmaf(xv[u], wvr[u].x, acc[j].x);           \
                        acc[j].y = fmaf(xv[u], wvr[u].y, acc[j].y);           \
                        acc[j].z = fmaf(xv[u], wvr[u].z, acc[j].z);           \
                        acc[j].w = fmaf(xv[u], wvr[u].w, acc[j].w);           \
                    }                                                         \
                }                                                             \
            }                                                                 \
        }                                                                     \
        buf ^= 1;                                                             \
    } while (0)

#pragma unroll
        for (int cc = 0; cc < NCHUNK; cc += 2) {
            WSTEP(sA0, sA1, cc);         // even chunks live in sA
            WSTEP(sB0, sB1, cc + 1);     // odd chunks live in sB
        }
#undef WSTEP
#undef WLOAD

#pragma unroll
        for (int j = 0; j < SMAX / 4; ++j) {
            int sl = wv4 + 4 * j;
            if (sl < ns) {
                int smp = slist[sbase + sl];
                *(float4*)(hout + (size_t)smp * H_DIM + hbase) = acc[j];
            }
        }
        if (sbase + SMAX < n) __syncthreads();       // next pass re-stages xlds
    }
}

// ---------------- threefry2x32, partitionable counter mode, key = (0, 1) --------
// (validated bit-exact — do not touch)
__device__ __forceinline__ uint32_t rotl32(uint32_t x, int r) {
    return (x << r) | (x >> (32 - r));
}

__device__ __forceinline__ uint32_t threefry_bits_part(uint32_t i) {
    uint32_t x0 = 0u;        // i >> 32 for i < 2^32
    uint32_t x1 = i;
    const uint32_t ks0 = 0u, ks1 = 1u, ks2 = 0x1BD11BDAu ^ 0u ^ 1u;
    x0 += ks0; x1 += ks1;
#define TFR(r) { x0 += x1; x1 = rotl32(x1, (r)); x1 ^= x0; }
    TFR(13) TFR(15) TFR(26) TFR(6)
    x0 += ks1; x1 += ks2 + 1u;
    TFR(17) TFR(29) TFR(16) TFR(24)
    x0 += ks2; x1 += ks0 + 2u;
    TFR(13) TFR(15) TFR(26) TFR(6)
    x0 += ks0; x1 += ks1 + 3u;
    TFR(17) TFR(29) TFR(16) TFR(24)
    x0 += ks1; x1 += ks2 + 4u;
    TFR(13) TFR(15) TFR(26) TFR(6)
    x0 += ks2; x1 += ks0 + 5u;
#undef TFR
    return x0 ^ x1;
}

// ---------------- K2: relu + fc2 + log_softmax + gumbel sample ----
// (validated round 8: inline bucketing, grid (task,4), slot = 4y+wv+16*rnd;
// absmax 0.0 — unchanged)
template <int KSP>
__global__ __launch_bounds__(256) void head_kernel(const int* __restrict__ raw,
                                                   const float* __restrict__ hpre,
                                                   const float* __restrict__ b1,
                                                   const float* __restrict__ w2,
                                                   const float* __restrict__ b2,
                                                   float* __restrict__ out) {
    __shared__ int slist[B_N];
    __shared__ int wcnt[4];
    __shared__ __align__(16) float w2l[H_DIM * A_DIM];   // 36 KB
    __shared__ float red[4][16][A_DIM];
    __shared__ float logits_lds[4][A_DIM];

    int t    = blockIdx.x;
    int y    = blockIdx.y;
    int tid  = threadIdx.x;
    int lane = tid & 63;
    int wv   = tid >> 6;

    int n = build_slist(raw, t, slist, wcnt, tid);
    if (4 * y >= n) return;                      // uniform block exit
    int K = (n - 4 * y - 1) / 16 + 1;            // uniform rounds per block

    // ---- stage w2[t] into LDS, coalesced: 2304 float4 over 256 threads ----
    const float4* g4 = (const float4*)(w2 + (size_t)t * (H_DIM * A_DIM));
    float4* l4 = (float4*)w2l;
#pragma unroll
    for (int i = 0; i < (H_DIM * A_DIM) / (256 * 4); ++i)   // 9 iters
        l4[i * 256 + tid] = g4[i * 256 + tid];
    __syncthreads();

    for (int rnd = 0; rnd < K; ++rnd) {
        int slot = 4 * y + wv + 16 * rnd;
        bool active = slot < n;
        int s = active ? slist[slot] : 0;

        // ---- h = relu(sum_k partial_k + b1) ----
        float hreg[H_DIM / 64];
#pragma unroll
        for (int kk = 0; kk < H_DIM / 64; ++kk) {
            int h = lane + 64 * kk;
            size_t p = (size_t)s * H_DIM + h;
            float v = b1[(size_t)t * H_DIM + h];
#pragma unroll
            for (int q = 0; q < KSP; ++q)
                v += hpre[(size_t)q * ((size_t)B_N * H_DIM) + p];
            hreg[kk] = fmaxf(v, 0.f);
        }

        // ---- per-lane partial logits from LDS ----
        float la[A_DIM];
#pragma unroll
        for (int a = 0; a < A_DIM; ++a) la[a] = 0.f;
#pragma unroll
        for (int kk = 0; kk < H_DIM / 64; ++kk) {
            int h = lane + 64 * kk;
            const float2* row = (const float2*)&w2l[h * A_DIM];
            float hk = hreg[kk];
#pragma unroll
            for (int a2 = 0; a2 < A_DIM / 2; ++a2) {
                float2 ww = row[a2];
                la[2 * a2]     = fmaf(hk, ww.x, la[2 * a2]);
                la[2 * a2 + 1] = fmaf(hk, ww.y, la[2 * a2 + 1]);
            }
        }

        // ---- reduce 64 partials: shfl_xor(1,2) -> 16 rows -> LDS -> 18-lane sum ----
#pragma unroll
        for (int a = 0; a < A_DIM; ++a) {
            la[a] += __shfl_xor(la[a], 1);
            la[a] += __shfl_xor(la[a], 2);
        }
        if ((lane & 3) == 0) {
            int g = lane >> 2;
#pragma unroll
            for (int a = 0; a < A_DIM; ++a) red[wv][g][a] = la[a];
        }
        __syncthreads();
        if (lane < A_DIM) {
            float sum = b2[(size_t)t * A_DIM + lane];
#pragma unroll
            for (int g = 0; g < 16; ++g) sum += red[wv][g][lane];
            logits_lds[wv][lane] = sum;
        }
        __syncthreads();

        // ---- tail: identical to the validated code ----
        float lg = (lane < A_DIM) ? logits_lds[wv][lane] : -INFINITY;

        float z = -INFINITY;
        if (lane < A_DIM) {
            uint32_t bits = threefry_bits_part((uint32_t)(s * A_DIM + lane));
            float f = __uint_as_float(0x3f800000u | (bits >> 9)) - 1.0f;
            float u = fmaxf(f, 1.17549435e-38f);   // jnp.finfo(f32).tiny
            float g = -logf(-logf(u));
            z = lg + g;
        }
        int idx = lane;
#pragma unroll
        for (int o = 1; o < 64; o <<= 1) {
            float oz = __shfl_xor(z, o);
            int   oi = __shfl_xor(idx, o);
            if (oz > z || (oz == z && oi < idx)) { z = oz; idx = oi; }
        }

        float mx = lg;
#pragma unroll
        for (int o = 1; o < 64; o <<= 1) mx = fmaxf(mx, __shfl_xor(mx, o));
        float e = (lane < A_DIM) ? expf(lg - mx) : 0.f;
#pragma unroll
        for (int o = 1; o < 64; o <<= 1) e += __shfl_xor(e, o);
        float lse = mx + logf(e);
        float lp = lg - lse;
        float c = (lane < A_DIM) ? expf(lp) * lp : 0.f;
#pragma unroll
        for (int o = 1; o < 64; o <<= 1) c += __shfl_xor(c, o);

        if (active && lane == 0) {
            out[s]             = (float)idx;                 // action
            out[B_N + s]       = logits_lds[wv][idx] - lse;  // log_prob
            out[2 * B_N + s]   = -c;                         // entropy
        }
        __syncthreads();   // logits/red reuse next round (uniform: K is block-uniform)
    }
}

extern "C" void kernel_launch(void* const* d_in, const int* in_sizes, int n_in,
                              void* d_out, int out_size, void* d_ws, size_t ws_size,
                              hipStream_t stream) {
    const float* xs      = (const float*)d_in[0];
    const int*   traw    = (const int*)d_in[1];   // int32 or int64 — detected on device
    const float* w1      = (const float*)d_in[2];
    const float* b1      = (const float*)d_in[3];
    const float* w2      = (const float*)d_in[4];
    const float* b2      = (const float*)d_in[5];
    float* out = (float*)d_out;
    char*  ws  = (char*)d_ws;

    const size_t part_bytes = (size_t)B_N * H_DIM * sizeof(float);   // 2 MB per K-split partial

    int ksp = 4;
    if (ws_size < 4 * part_bytes) ksp = 2;
    if (ws_size < 2 * part_bytes) ksp = 1;

    float* hpre = (float*)ws;

    if (ksp == 4) {
        fc1_kernel<4><<<dim3(T_N, 2, 4), 256, 0, stream>>>(xs, w1, traw, hpre);
        head_kernel<4><<<dim3(T_N, 4), 256, 0, stream>>>(traw, hpre, b1, w2, b2, out);
    } else if (ksp == 2) {
        fc1_kernel<2><<<dim3(T_N, 2, 2), 256, 0, stream>>>(xs, w1, traw, hpre);
        head_kernel<2><<<dim3(T_N, 4), 256, 0, stream>>>(traw, hpre, b1, w2, b2, out);
    } else {
        fc1_kernel<1><<<dim3(T_N, 2, 1), 256, 0, stream>>>(xs, w1, traw, hpre);
        head_kernel<1><<<dim3(T_N, 4), 256, 0, stream>>>(traw, hpre, b1, w2, b2, out);
    }
}